// Round 1
// baseline (424.148 us; speedup 1.0000x reference)
//
#include <hip/hip_runtime.h>
#include <math.h>

#define IMGS 64
#define HWDIM 512
#define KLEN 31
#define RAD 15
#define EPSV 1e-3f

// ws layout (in floats):
//   [0..31)     : 1D separable weights s[i]  (kernel[i][j] = s_i*s_j)
//   [32..160)   : per-image min/max as int bits, 2 ints per image (64 images)
//   [1024.. )   : soft buffer, 64*512*512 floats (64 MB)
// d_out doubles as scratch for the horizontal-conv intermediate.

__global__ __launch_bounds__(128) void init_k(const float* __restrict__ gk,
                                              float* __restrict__ w,
                                              int* __restrict__ mm) {
    int t = threadIdx.x;
    if (t < KLEN) w[t] = sqrtf(gk[t * KLEN + t]);   // diag of s_i*s_j = s_i^2
    if (t < IMGS) { mm[2 * t] = 0x7F800000; mm[2 * t + 1] = 0; }  // +inf / 0
}

// Horizontal 31-tap conv with clip fused. One block = 2 rows of 512.
__global__ __launch_bounds__(256) void hconv_k(const float* __restrict__ in,
                                               float* __restrict__ tmp,
                                               const float* __restrict__ wg) {
    __shared__ float rows[2][HWDIM + 2 * RAD + 2];  // stride 544 (16B aligned)
    __shared__ float w[KLEN];
    const int t = threadIdx.x;
    if (t < KLEN) w[t] = wg[t];
    const size_t row0 = (size_t)blockIdx.x * 2;
    {
        const float4* src = (const float4*)(in + row0 * HWDIM);
        float4 v = src[t];                       // 256 float4 = 2 rows
        const int rr = t >> 7;
        const int cc = (t & 127) << 2;
        float* p = &rows[rr][RAD + cc];
        p[0] = fminf(fmaxf(v.x, 0.f), 1.f);
        p[1] = fminf(fmaxf(v.y, 0.f), 1.f);
        p[2] = fminf(fmaxf(v.z, 0.f), 1.f);
        p[3] = fminf(fmaxf(v.w, 0.f), 1.f);
    }
    const int r = t >> 7;
    const int j = t & 127;
    if (j < RAD) { rows[r][j] = 0.f; rows[r][RAD + HWDIM + j] = 0.f; }
    __syncthreads();
    // register sliding window: 36 floats cover outputs 4j..4j+3
    float vv[36];
#pragma unroll
    for (int m = 0; m < 9; ++m) {
        const float4 q = *(const float4*)&rows[r][(j << 2) + (m << 2)];
        vv[4 * m + 0] = q.x; vv[4 * m + 1] = q.y;
        vv[4 * m + 2] = q.z; vv[4 * m + 3] = q.w;
    }
    float4 o;
    float* op = &o.x;
#pragma unroll
    for (int i = 0; i < 4; ++i) {
        float acc = 0.f;
#pragma unroll
        for (int k = 0; k < KLEN; ++k) acc += vv[i + k] * w[k];
        op[i] = acc;
    }
    float4* dst = (float4*)(tmp + (row0 + r) * HWDIM);
    dst[j] = o;
}

// Vertical 31-tap conv + fused per-image min/max. Block (64,4): 64x32 tile.
__global__ __launch_bounds__(256) void vconv_k(const float* __restrict__ tmp,
                                               float* __restrict__ soft,
                                               const float* __restrict__ wg,
                                               int* __restrict__ mm) {
    __shared__ float tile[32 + 2 * RAD][64];   // 62 x 64 floats = 15.9 KB
    __shared__ float w[KLEN];
    const int tx = threadIdx.x;                // 0..63
    const int ty = threadIdx.y;                // 0..3
    const int tid = ty * 64 + tx;
    if (tid < KLEN) w[tid] = wg[tid];
    const int img = blockIdx.z;
    const int x0 = blockIdx.x << 6;
    const int y0 = blockIdx.y << 5;
    const float* src = tmp + (size_t)img * HWDIM * HWDIM;
    // stage 62 rows x 64 cols (with zero halo) = 992 float4s
#pragma unroll
    for (int it = 0; it < 4; ++it) {
        int idx = tid + it * 256;
        if (idx < 992) {
            int rr = idx >> 4;
            int c4 = idx & 15;
            int y = y0 - RAD + rr;
            float4 v = make_float4(0.f, 0.f, 0.f, 0.f);
            if (y >= 0 && y < HWDIM)
                v = *(const float4*)(src + (size_t)y * HWDIM + x0 + (c4 << 2));
            *(float4*)&tile[rr][c4 << 2] = v;
        }
    }
    __syncthreads();
    // register sliding window down the column: 38 values -> 8 outputs
    float win[38];
    const int ybase = ty << 3;
#pragma unroll
    for (int k = 0; k < 38; ++k) win[k] = tile[ybase + k][tx];
    float* dst = soft + (size_t)img * HWDIM * HWDIM;
    float lmin = INFINITY, lmax = -INFINITY;
#pragma unroll
    for (int i = 0; i < 8; ++i) {
        float acc = 0.f;
#pragma unroll
        for (int k = 0; k < KLEN; ++k) acc += win[i + k] * w[k];
        dst[(size_t)(y0 + ybase + i) * HWDIM + x0 + tx] = acc;
        lmin = fminf(lmin, acc);
        lmax = fmaxf(lmax, acc);
    }
    // wave-64 butterfly reduce, then one atomic pair per wave.
#pragma unroll
    for (int off = 1; off < 64; off <<= 1) {
        lmin = fminf(lmin, __shfl_xor(lmin, off, 64));
        lmax = fmaxf(lmax, __shfl_xor(lmax, off, 64));
    }
    if (tx == 0) {
        // all values >= 0 -> float ordering == int-bits ordering
        atomicMin(&mm[2 * img], __float_as_int(lmin));
        atomicMax(&mm[2 * img + 1], __float_as_int(lmax));
    }
}

// out = max((soft - mn) / max(mx - mn, eps), clip(attn,0,1))
__global__ __launch_bounds__(256) void final_k(const float* __restrict__ soft,
                                               const float* __restrict__ attn,
                                               float* __restrict__ out,
                                               const int* __restrict__ mm) {
    const int img = blockIdx.x >> 8;           // 256 blocks of 1024 elems/image
    const float mn = __int_as_float(mm[2 * img]);
    const float mx = __int_as_float(mm[2 * img + 1]);
    const float inv = 1.0f / fmaxf(mx - mn, EPSV);
    const size_t base = ((size_t)blockIdx.x << 10) + ((size_t)threadIdx.x << 2);
    float4 s = *(const float4*)(soft + base);
    float4 a = *(const float4*)(attn + base);
    float4 o;
    o.x = fmaxf((s.x - mn) * inv, fminf(fmaxf(a.x, 0.f), 1.f));
    o.y = fmaxf((s.y - mn) * inv, fminf(fmaxf(a.y, 0.f), 1.f));
    o.z = fmaxf((s.z - mn) * inv, fminf(fmaxf(a.z, 0.f), 1.f));
    o.w = fmaxf((s.w - mn) * inv, fminf(fmaxf(a.w, 0.f), 1.f));
    *(float4*)(out + base) = o;
}

extern "C" void kernel_launch(void* const* d_in, const int* in_sizes, int n_in,
                              void* d_out, int out_size, void* d_ws, size_t ws_size,
                              hipStream_t stream) {
    const float* attn = (const float*)d_in[0];
    const float* gk   = (const float*)d_in[1];
    float* out  = (float*)d_out;
    float* wsf  = (float*)d_ws;
    float* w1d  = wsf;
    int*   mm   = (int*)(wsf + 32);
    float* soft = wsf + 1024;          // 64 MB soft buffer
    float* tmp  = out;                 // d_out as horizontal-conv scratch

    init_k<<<1, 128, 0, stream>>>(gk, w1d, mm);
    hconv_k<<<IMGS * HWDIM / 2, 256, 0, stream>>>(attn, tmp, w1d);
    vconv_k<<<dim3(8, 16, IMGS), dim3(64, 4), 0, stream>>>(tmp, soft, w1d, mm);
    final_k<<<IMGS * HWDIM * HWDIM / 1024, 256, 0, stream>>>(soft, attn, out, mm);
}

// Round 2
// 146.211 us; speedup vs baseline: 2.9009x; 2.9009x over previous
//
#include <hip/hip_runtime.h>
#include <math.h>

#define IMGS 64
#define HWDIM 512
#define KLEN 31
#define RAD 15
#define EPSV 1e-3f

// ws layout (in floats):
//   [0..31)      : 1D separable weights s[i]  (kernel[i][j] = s_i*s_j)
//   [32..2080)   : per-image min/max as int bits, padded 32 ints (128 B) per image
//   [4096.. )    : soft buffer, 64*512*512 floats (64 MB)
// d_out doubles as scratch for the horizontal-conv intermediate.
#define MM_STRIDE 32   // ints per image slot (one 128B cache line each)

__global__ __launch_bounds__(128) void init_k(const float* __restrict__ gk,
                                              float* __restrict__ w,
                                              int* __restrict__ mm) {
    int t = threadIdx.x;
    if (t < KLEN) w[t] = sqrtf(gk[t * KLEN + t]);   // diag of s_i*s_j = s_i^2
    if (t < IMGS) { mm[t * MM_STRIDE] = 0x7F800000; mm[t * MM_STRIDE + 1] = 0; }
}

// Horizontal 31-tap conv with clip fused. One block = 2 rows of 512.
__global__ __launch_bounds__(256) void hconv_k(const float* __restrict__ in,
                                               float* __restrict__ tmp,
                                               const float* __restrict__ wg) {
    __shared__ float rows[2][HWDIM + 2 * RAD + 2];  // stride 544 (16B aligned)
    __shared__ float w[KLEN];
    const int t = threadIdx.x;
    if (t < KLEN) w[t] = wg[t];
    const size_t row0 = (size_t)blockIdx.x * 2;
    {
        const float4* src = (const float4*)(in + row0 * HWDIM);
        float4 v = src[t];                       // 256 float4 = 2 rows
        const int rr = t >> 7;
        const int cc = (t & 127) << 2;
        float* p = &rows[rr][RAD + cc];
        p[0] = fminf(fmaxf(v.x, 0.f), 1.f);
        p[1] = fminf(fmaxf(v.y, 0.f), 1.f);
        p[2] = fminf(fmaxf(v.z, 0.f), 1.f);
        p[3] = fminf(fmaxf(v.w, 0.f), 1.f);
    }
    const int r = t >> 7;
    const int j = t & 127;
    if (j < RAD) { rows[r][j] = 0.f; rows[r][RAD + HWDIM + j] = 0.f; }
    __syncthreads();
    // register sliding window: 36 floats cover outputs 4j..4j+3
    float vv[36];
#pragma unroll
    for (int m = 0; m < 9; ++m) {
        const float4 q = *(const float4*)&rows[r][(j << 2) + (m << 2)];
        vv[4 * m + 0] = q.x; vv[4 * m + 1] = q.y;
        vv[4 * m + 2] = q.z; vv[4 * m + 3] = q.w;
    }
    float4 o;
    float* op = &o.x;
#pragma unroll
    for (int i = 0; i < 4; ++i) {
        float acc = 0.f;
#pragma unroll
        for (int k = 0; k < KLEN; ++k) acc += vv[i + k] * w[k];
        op[i] = acc;
    }
    float4* dst = (float4*)(tmp + (row0 + r) * HWDIM);
    dst[j] = o;
}

// Vertical 31-tap conv + fused per-image min/max. Block (64,4): 64x32 tile.
__global__ __launch_bounds__(256) void vconv_k(const float* __restrict__ tmp,
                                               float* __restrict__ soft,
                                               const float* __restrict__ wg,
                                               int* __restrict__ mm) {
    __shared__ float tile[32 + 2 * RAD][64];   // 62 x 64 floats = 15.9 KB
    __shared__ float w[KLEN];
    __shared__ float smin[4], smax[4];
    const int tx = threadIdx.x;                // 0..63
    const int ty = threadIdx.y;                // 0..3
    const int tid = ty * 64 + tx;
    if (tid < KLEN) w[tid] = wg[tid];
    const int img = blockIdx.z;
    const int x0 = blockIdx.x << 6;
    const int y0 = blockIdx.y << 5;
    const float* src = tmp + (size_t)img * HWDIM * HWDIM;
    // stage 62 rows x 64 cols (with zero halo) = 992 float4s
#pragma unroll
    for (int it = 0; it < 4; ++it) {
        int idx = tid + it * 256;
        if (idx < 992) {
            int rr = idx >> 4;
            int c4 = idx & 15;
            int y = y0 - RAD + rr;
            float4 v = make_float4(0.f, 0.f, 0.f, 0.f);
            if (y >= 0 && y < HWDIM)
                v = *(const float4*)(src + (size_t)y * HWDIM + x0 + (c4 << 2));
            *(float4*)&tile[rr][c4 << 2] = v;
        }
    }
    __syncthreads();
    // register sliding window down the column: 38 values -> 8 outputs
    float win[38];
    const int ybase = ty << 3;
#pragma unroll
    for (int k = 0; k < 38; ++k) win[k] = tile[ybase + k][tx];
    float* dst = soft + (size_t)img * HWDIM * HWDIM;
    float lmin = INFINITY, lmax = -INFINITY;
#pragma unroll
    for (int i = 0; i < 8; ++i) {
        float acc = 0.f;
#pragma unroll
        for (int k = 0; k < KLEN; ++k) acc += win[i + k] * w[k];
        dst[(size_t)(y0 + ybase + i) * HWDIM + x0 + tx] = acc;
        lmin = fminf(lmin, acc);
        lmax = fmaxf(lmax, acc);
    }
    // wave-64 butterfly reduce -> per-block LDS reduce -> ONE atomic pair/block
#pragma unroll
    for (int off = 1; off < 64; off <<= 1) {
        lmin = fminf(lmin, __shfl_xor(lmin, off, 64));
        lmax = fmaxf(lmax, __shfl_xor(lmax, off, 64));
    }
    if (tx == 0) { smin[ty] = lmin; smax[ty] = lmax; }
    __syncthreads();
    if (tid == 0) {
        float bmin = fminf(fminf(smin[0], smin[1]), fminf(smin[2], smin[3]));
        float bmax = fmaxf(fmaxf(smax[0], smax[1]), fmaxf(smax[2], smax[3]));
        // all values >= 0 -> float ordering == int-bits ordering
        atomicMin(&mm[img * MM_STRIDE], __float_as_int(bmin));
        atomicMax(&mm[img * MM_STRIDE + 1], __float_as_int(bmax));
    }
}

// out = max((soft - mn) / max(mx - mn, eps), clip(attn,0,1))
__global__ __launch_bounds__(256) void final_k(const float* __restrict__ soft,
                                               const float* __restrict__ attn,
                                               float* __restrict__ out,
                                               const int* __restrict__ mm) {
    const int img = blockIdx.x >> 8;           // 256 blocks of 1024 elems/image
    const float mn = __int_as_float(mm[img * MM_STRIDE]);
    const float mx = __int_as_float(mm[img * MM_STRIDE + 1]);
    const float inv = 1.0f / fmaxf(mx - mn, EPSV);
    const size_t base = ((size_t)blockIdx.x << 10) + ((size_t)threadIdx.x << 2);
    float4 s = *(const float4*)(soft + base);
    float4 a = *(const float4*)(attn + base);
    float4 o;
    o.x = fmaxf((s.x - mn) * inv, fminf(fmaxf(a.x, 0.f), 1.f));
    o.y = fmaxf((s.y - mn) * inv, fminf(fmaxf(a.y, 0.f), 1.f));
    o.z = fmaxf((s.z - mn) * inv, fminf(fmaxf(a.z, 0.f), 1.f));
    o.w = fmaxf((s.w - mn) * inv, fminf(fmaxf(a.w, 0.f), 1.f));
    *(float4*)(out + base) = o;
}

extern "C" void kernel_launch(void* const* d_in, const int* in_sizes, int n_in,
                              void* d_out, int out_size, void* d_ws, size_t ws_size,
                              hipStream_t stream) {
    const float* attn = (const float*)d_in[0];
    const float* gk   = (const float*)d_in[1];
    float* out  = (float*)d_out;
    float* wsf  = (float*)d_ws;
    float* w1d  = wsf;
    int*   mm   = (int*)(wsf + 32);
    float* soft = wsf + 4096;          // 64 MB soft buffer
    float* tmp  = out;                 // d_out as horizontal-conv scratch

    init_k<<<1, 128, 0, stream>>>(gk, w1d, mm);
    hconv_k<<<IMGS * HWDIM / 2, 256, 0, stream>>>(attn, tmp, w1d);
    vconv_k<<<dim3(8, 16, IMGS), dim3(64, 4), 0, stream>>>(tmp, soft, w1d, mm);
    final_k<<<IMGS * HWDIM * HWDIM / 1024, 256, 0, stream>>>(soft, attn, out, mm);
}

// Round 3
// 122.046 us; speedup vs baseline: 3.4753x; 1.1980x over previous
//
#include <hip/hip_runtime.h>
#include <math.h>

#define IMGS 64
#define HWDIM 512
#define KLEN 31
#define RAD 15
#define EPSV 1e-3f

// ws layout (in floats):
//   [0..31)      : 1D separable weights s[i]  (kernel[i][j] = s_i*s_j)
//   [32..2080)   : per-image min/max as int bits, padded 32 ints (128 B) per image
//   [4096.. )    : soft buffer, 64*512*512 floats (64 MB)
// d_out doubles as scratch for the horizontal-conv intermediate.
#define MM_STRIDE 32   // ints per image slot (one 128B cache line each)

__global__ __launch_bounds__(128) void init_k(const float* __restrict__ gk,
                                              float* __restrict__ w,
                                              int* __restrict__ mm) {
    int t = threadIdx.x;
    if (t < KLEN) w[t] = sqrtf(gk[t * KLEN + t]);   // diag of s_i*s_j = s_i^2
    if (t < IMGS) { mm[t * MM_STRIDE] = 0x7F800000; mm[t * MM_STRIDE + 1] = 0; }
}

// Horizontal 31-tap conv with clip fused. One block = 8 rows of 512.
__global__ __launch_bounds__(256) void hconv_k(const float* __restrict__ in,
                                               float* __restrict__ tmp,
                                               const float* __restrict__ wg) {
    __shared__ float rows[8][HWDIM + 2 * RAD + 2];  // stride 544 (16B aligned)
    const int t = threadIdx.x;
    const size_t row0 = (size_t)blockIdx.x * 8;
    const float4* src = (const float4*)(in + row0 * HWDIM);
#pragma unroll
    for (int it = 0; it < 4; ++it) {
        const int idx = t + it * 256;            // 0..1023 = 8 rows x 128 f4
        float4 v = src[idx];
        const int rr = idx >> 7;
        const int cc = (idx & 127) << 2;
        float* p = &rows[rr][RAD + cc];
        p[0] = fminf(fmaxf(v.x, 0.f), 1.f);
        p[1] = fminf(fmaxf(v.y, 0.f), 1.f);
        p[2] = fminf(fmaxf(v.z, 0.f), 1.f);
        p[3] = fminf(fmaxf(v.w, 0.f), 1.f);
    }
    {   // zero halos: 8 rows x (15 left + 15 right)
        const int rr = t >> 5;
        const int q = t & 31;
        if (q < RAD) rows[rr][q] = 0.f;
        else if (q >= 16 && q < 31) rows[rr][HWDIM + RAD + (q - 16)] = 0.f;
    }
    __syncthreads();
#pragma unroll
    for (int it = 0; it < 4; ++it) {
        const int idx = t + it * 256;            // 8 rows x 128 groups
        const int r = idx >> 7;
        const int g = idx & 127;
        float vv[36];
#pragma unroll
        for (int m = 0; m < 9; ++m) {
            const float4 q = *(const float4*)&rows[r][(g << 2) + (m << 2)];
            vv[4 * m + 0] = q.x; vv[4 * m + 1] = q.y;
            vv[4 * m + 2] = q.z; vv[4 * m + 3] = q.w;
        }
        float4 o;
        float* op = &o.x;
#pragma unroll
        for (int i = 0; i < 4; ++i) {
            float acc = 0.f;
#pragma unroll
            for (int k = 0; k < KLEN; ++k) acc += vv[i + k] * wg[k];
            op[i] = acc;
        }
        *(float4*)(tmp + (row0 + r) * HWDIM + (g << 2)) = o;
    }
}

// Vertical 31-tap conv + fused per-image min/max. Block (64,4): 64x64 tile.
__global__ __launch_bounds__(256) void vconv_k(const float* __restrict__ tmp,
                                               float* __restrict__ soft,
                                               const float* __restrict__ wg,
                                               int* __restrict__ mm) {
    __shared__ float tile[64 + 2 * RAD][64];   // 94 x 64 floats = 23.5 KB
    __shared__ float smin[4], smax[4];
    const int tx = threadIdx.x;                // 0..63
    const int ty = threadIdx.y;                // 0..3
    const int tid = ty * 64 + tx;
    const int img = blockIdx.z;
    const int x0 = blockIdx.x << 6;
    const int y0 = blockIdx.y << 6;
    const float* src = tmp + (size_t)img * HWDIM * HWDIM;
    // stage 94 rows x 64 cols (with zero halo) = 1504 float4s
#pragma unroll
    for (int it = 0; it < 6; ++it) {
        const int idx = tid + it * 256;
        if (idx < 94 * 16) {
            const int rr = idx >> 4;
            const int c4 = idx & 15;
            const int y = y0 - RAD + rr;
            float4 v = make_float4(0.f, 0.f, 0.f, 0.f);
            if (y >= 0 && y < HWDIM)
                v = *(const float4*)(src + (size_t)y * HWDIM + x0 + (c4 << 2));
            *(float4*)&tile[rr][c4 << 2] = v;
        }
    }
    __syncthreads();
    // register sliding window down the column: 46 values -> 16 outputs
    float win[46];
    const int ybase = ty << 4;
#pragma unroll
    for (int k = 0; k < 46; ++k) win[k] = tile[ybase + k][tx];
    float* dst = soft + (size_t)img * HWDIM * HWDIM;
    float lmin = INFINITY, lmax = -INFINITY;
#pragma unroll
    for (int i = 0; i < 16; ++i) {
        float acc = 0.f;
#pragma unroll
        for (int k = 0; k < KLEN; ++k) acc += win[i + k] * wg[k];
        dst[(size_t)(y0 + ybase + i) * HWDIM + x0 + tx] = acc;
        lmin = fminf(lmin, acc);
        lmax = fmaxf(lmax, acc);
    }
    // wave-64 butterfly reduce -> per-block LDS reduce -> ONE atomic pair/block
#pragma unroll
    for (int off = 1; off < 64; off <<= 1) {
        lmin = fminf(lmin, __shfl_xor(lmin, off, 64));
        lmax = fmaxf(lmax, __shfl_xor(lmax, off, 64));
    }
    if (tx == 0) { smin[ty] = lmin; smax[ty] = lmax; }
    __syncthreads();
    if (tid == 0) {
        float bmin = fminf(fminf(smin[0], smin[1]), fminf(smin[2], smin[3]));
        float bmax = fmaxf(fmaxf(smax[0], smax[1]), fmaxf(smax[2], smax[3]));
        // all values >= 0 -> float ordering == int-bits ordering
        atomicMin(&mm[img * MM_STRIDE], __float_as_int(bmin));
        atomicMax(&mm[img * MM_STRIDE + 1], __float_as_int(bmax));
    }
}

// out = max((soft - mn) / max(mx - mn, eps), clip(attn,0,1)). 2 float4/thread.
__global__ __launch_bounds__(256) void final_k(const float* __restrict__ soft,
                                               const float* __restrict__ attn,
                                               float* __restrict__ out,
                                               const int* __restrict__ mm) {
    const int img = blockIdx.x >> 7;           // 128 blocks of 2048 elems/image
    const float mn = __int_as_float(mm[img * MM_STRIDE]);
    const float mx = __int_as_float(mm[img * MM_STRIDE + 1]);
    const float inv = 1.0f / fmaxf(mx - mn, EPSV);
    const size_t base0 = ((size_t)blockIdx.x << 11) + ((size_t)threadIdx.x << 2);
#pragma unroll
    for (int h = 0; h < 2; ++h) {
        const size_t base = base0 + (size_t)h * 1024;
        float4 s = *(const float4*)(soft + base);
        float4 a = *(const float4*)(attn + base);
        float4 o;
        o.x = fmaxf((s.x - mn) * inv, fminf(fmaxf(a.x, 0.f), 1.f));
        o.y = fmaxf((s.y - mn) * inv, fminf(fmaxf(a.y, 0.f), 1.f));
        o.z = fmaxf((s.z - mn) * inv, fminf(fmaxf(a.z, 0.f), 1.f));
        o.w = fmaxf((s.w - mn) * inv, fminf(fmaxf(a.w, 0.f), 1.f));
        *(float4*)(out + base) = o;
    }
}

extern "C" void kernel_launch(void* const* d_in, const int* in_sizes, int n_in,
                              void* d_out, int out_size, void* d_ws, size_t ws_size,
                              hipStream_t stream) {
    const float* attn = (const float*)d_in[0];
    const float* gk   = (const float*)d_in[1];
    float* out  = (float*)d_out;
    float* wsf  = (float*)d_ws;
    float* w1d  = wsf;
    int*   mm   = (int*)(wsf + 32);
    float* soft = wsf + 4096;          // 64 MB soft buffer
    float* tmp  = out;                 // d_out as horizontal-conv scratch

    init_k<<<1, 128, 0, stream>>>(gk, w1d, mm);
    hconv_k<<<IMGS * HWDIM / 8, 256, 0, stream>>>(attn, tmp, w1d);
    vconv_k<<<dim3(8, 8, IMGS), dim3(64, 4), 0, stream>>>(tmp, soft, w1d, mm);
    final_k<<<IMGS * HWDIM * HWDIM / 2048, 256, 0, stream>>>(soft, attn, out, mm);
}

// Round 5
// 115.982 us; speedup vs baseline: 3.6570x; 1.0523x over previous
//
#include <hip/hip_runtime.h>
#include <math.h>

#define IMGS 64
#define HWDIM 512
#define KLEN 31
#define RAD 15
#define EPSV 1e-3f
#define MM_STRIDE 32   // ints per image slot (one 128B cache line each)

// ws layout (floats):
//   [0..31)     : separable weights s[i]  (kernel[i][j] = s_i*s_j)
//   [32..2080)  : per-image min/max int bits, 32-int stride
//   [4096..)    : tmp (h-conv intermediate), 64 MB
// d_out carries the pre-norm v-conv result, normalized in place by final_k.

__global__ __launch_bounds__(128) void init_k(const float* __restrict__ gk,
                                              float* __restrict__ w,
                                              int* __restrict__ mm) {
    int t = threadIdx.x;
    if (t < KLEN) w[t] = sqrtf(gk[t * KLEN + t]);   // diag of s_i*s_j = s_i^2
    if (t < IMGS) { mm[t * MM_STRIDE] = 0x7F800000; mm[t * MM_STRIDE + 1] = 0; }
}

// Horizontal 31-tap conv, clip fused. Barrier-free: 9 direct float4 loads
// (same row -> L1-hot), 4 outputs per thread. One wave = half a row.
__global__ __launch_bounds__(256) void hconv_k(const float* __restrict__ in,
                                               float* __restrict__ tmp,
                                               const float* __restrict__ wg) {
    const int gid = blockIdx.x * 256 + threadIdx.x;
    const int row = gid >> 7;                    // 0..32767 (img*512+y)
    const int g   = gid & 127;                   // float4 group in row
    const float4* src = (const float4*)(in + (size_t)row * HWDIM);
    float vv[36];
#pragma unroll
    for (int m = 0; m < 9; ++m) {
        const int gm = g - 4 + m;
        float4 v = make_float4(0.f, 0.f, 0.f, 0.f);
        if (gm >= 0 && gm < 128) v = src[gm];
        vv[4 * m + 0] = fminf(fmaxf(v.x, 0.f), 1.f);
        vv[4 * m + 1] = fminf(fmaxf(v.y, 0.f), 1.f);
        vv[4 * m + 2] = fminf(fmaxf(v.z, 0.f), 1.f);
        vv[4 * m + 3] = fminf(fmaxf(v.w, 0.f), 1.f);
    }
    float4 o;
    float* op = &o.x;
#pragma unroll
    for (int i = 0; i < 4; ++i) {
        float acc = 0.f;
#pragma unroll
        for (int k = 0; k < KLEN; ++k) acc += vv[i + 1 + k] * wg[k];
        op[i] = acc;
    }
    *(float4*)(tmp + (size_t)row * HWDIM + (g << 2)) = o;
}

// Vertical 31-tap conv + per-image min/max. Barrier-free compute: each thread
// reads its 46-row column window directly from global (L3-served, coalesced
// 256B/wave row segments), streams 16 pre-norm outputs to `out`.
__global__ __launch_bounds__(256) void vconv_k(const float* __restrict__ tmp,
                                               float* __restrict__ out,
                                               const float* __restrict__ wg,
                                               int* __restrict__ mm) {
    __shared__ float smin[4], smax[4];
    const int t  = threadIdx.x;
    const int tx = t & 63;
    const int ty = t >> 6;
    const int bid = blockIdx.x;
    const int img = bid >> 6;                    // 64 blocks per image
    const int ti  = bid & 63;                    // 8x8 tiles of 64x64
    const int x0 = (ti & 7) << 6;
    const int y0 = (ti >> 3) << 6;
    const float* src = tmp + ((size_t)img << 18);
    float* dst = out + ((size_t)img << 18);
    const int col = x0 + tx;
    const int rb  = y0 + (ty << 4) - RAD;        // window start row
    float win[46];
#pragma unroll
    for (int k = 0; k < 46; ++k) {
        const int y = rb + k;                    // wave-uniform condition
        win[k] = (y >= 0 && y < HWDIM) ? src[(size_t)y * HWDIM + col] : 0.f;
    }
    float lmin = INFINITY, lmax = -INFINITY;
#pragma unroll
    for (int i = 0; i < 16; ++i) {
        float a = 0.f;
#pragma unroll
        for (int k = 0; k < KLEN; ++k) a += win[i + k] * wg[k];
        dst[(size_t)(rb + RAD + i) * HWDIM + col] = a;
        lmin = fminf(lmin, a);
        lmax = fmaxf(lmax, a);
    }
    // wave butterfly -> block LDS reduce -> one atomic pair per block
#pragma unroll
    for (int off = 1; off < 64; off <<= 1) {
        lmin = fminf(lmin, __shfl_xor(lmin, off, 64));
        lmax = fmaxf(lmax, __shfl_xor(lmax, off, 64));
    }
    if (tx == 0) { smin[ty] = lmin; smax[ty] = lmax; }
    __syncthreads();
    if (t == 0) {
        float bmin = fminf(fminf(smin[0], smin[1]), fminf(smin[2], smin[3]));
        float bmax = fmaxf(fmaxf(smax[0], smax[1]), fmaxf(smax[2], smax[3]));
        // all values >= 0 -> float ordering == int-bits ordering
        atomicMin(&mm[img * MM_STRIDE], __float_as_int(bmin));
        atomicMax(&mm[img * MM_STRIDE + 1], __float_as_int(bmax));
    }
}

// out = max((out - mn) / max(mx - mn, eps), clip(attn,0,1)), in place.
__global__ __launch_bounds__(256) void final_k(const float* __restrict__ attn,
                                               float* __restrict__ out,
                                               const int* __restrict__ mm) {
    const int img = blockIdx.x >> 7;             // 128 blocks of 2048 elems/image
    const float mn = __int_as_float(mm[img * MM_STRIDE]);
    const float mx = __int_as_float(mm[img * MM_STRIDE + 1]);
    const float inv = 1.0f / fmaxf(mx - mn, EPSV);
    const size_t base0 = ((size_t)blockIdx.x << 11) + ((size_t)threadIdx.x << 2);
#pragma unroll
    for (int h = 0; h < 2; ++h) {
        const size_t base = base0 + (size_t)h * 1024;
        float4 s = *(const float4*)(out + base);
        float4 a = *(const float4*)(attn + base);
        float4 o;
        o.x = fmaxf((s.x - mn) * inv, fminf(fmaxf(a.x, 0.f), 1.f));
        o.y = fmaxf((s.y - mn) * inv, fminf(fmaxf(a.y, 0.f), 1.f));
        o.z = fmaxf((s.z - mn) * inv, fminf(fmaxf(a.z, 0.f), 1.f));
        o.w = fmaxf((s.w - mn) * inv, fminf(fmaxf(a.w, 0.f), 1.f));
        *(float4*)(out + base) = o;
    }
}

extern "C" void kernel_launch(void* const* d_in, const int* in_sizes, int n_in,
                              void* d_out, int out_size, void* d_ws, size_t ws_size,
                              hipStream_t stream) {
    const float* attn = (const float*)d_in[0];
    const float* gk   = (const float*)d_in[1];
    float* out  = (float*)d_out;
    float* wsf  = (float*)d_ws;
    float* w1d  = wsf;
    int*   mm   = (int*)(wsf + 32);
    float* tmp  = wsf + 4096;          // 64 MB h-conv intermediate

    init_k<<<1, 128, 0, stream>>>(gk, w1d, mm);
    hconv_k<<<IMGS * HWDIM * 128 / 256, 256, 0, stream>>>(attn, tmp, w1d);
    vconv_k<<<IMGS * 64, 256, 0, stream>>>(tmp, out, w1d, mm);
    final_k<<<IMGS * HWDIM * HWDIM / 2048, 256, 0, stream>>>(attn, out, mm);
}

// Round 6
// 111.075 us; speedup vs baseline: 3.8186x; 1.0442x over previous
//
#include <hip/hip_runtime.h>
#include <math.h>

#define IMGS 64
#define HWDIM 512
#define KLEN 31
#define RAD 15
#define EPSV 1e-3f
#define MM_STRIDE 32   // ints per image slot (one 128B cache line each)

// ws layout (floats):
//   [0..31)     : separable weights s[i]  (kernel[i][j] = s_i*s_j)
//   [32..2080)  : per-image min/max int bits, 32-int stride
//   [4096..)    : tmp (h-conv intermediate), 64 MB
// d_out carries the pre-norm v-conv result, normalized in place by final_k.

__global__ __launch_bounds__(128) void init_k(const float* __restrict__ gk,
                                              float* __restrict__ w,
                                              int* __restrict__ mm) {
    int t = threadIdx.x;
    if (t < KLEN) w[t] = sqrtf(gk[t * KLEN + t]);   // diag of s_i*s_j = s_i^2
    if (t < IMGS) { mm[t * MM_STRIDE] = 0x7F800000; mm[t * MM_STRIDE + 1] = 0; }
}

// Horizontal 31-tap conv, clip fused. Barrier-free. 16 outputs per thread:
// 12 float4 window loads -> 496 FMA. 32 threads per row.
__global__ __launch_bounds__(256) void hconv_k(const float* __restrict__ in,
                                               float* __restrict__ tmp,
                                               const float* __restrict__ wg) {
    const int gid = blockIdx.x * 256 + threadIdx.x;
    const int row = gid >> 5;                    // img*512 + y
    const int q   = gid & 31;                    // 16-col output group
    const float4* src = (const float4*)(in + (size_t)row * HWDIM);
    float vv[48];
#pragma unroll
    for (int m = 0; m < 12; ++m) {
        const int gm = (q << 2) - 4 + m;
        float4 v = make_float4(0.f, 0.f, 0.f, 0.f);
        if (gm >= 0 && gm < 128) v = src[gm];
        vv[4 * m + 0] = fminf(fmaxf(v.x, 0.f), 1.f);
        vv[4 * m + 1] = fminf(fmaxf(v.y, 0.f), 1.f);
        vv[4 * m + 2] = fminf(fmaxf(v.z, 0.f), 1.f);
        vv[4 * m + 3] = fminf(fmaxf(v.w, 0.f), 1.f);
    }
    float4* dst = (float4*)(tmp + (size_t)row * HWDIM + (q << 4));
#pragma unroll
    for (int d = 0; d < 4; ++d) {
        float4 o;
        float* op = &o.x;
#pragma unroll
        for (int s = 0; s < 4; ++s) {
            const int i = 4 * d + s;
            float acc = 0.f;
#pragma unroll
            for (int k = 0; k < KLEN; ++k) acc += vv[i + 1 + k] * wg[k];
            op[s] = acc;
        }
        dst[d] = o;
    }
}

// Vertical 31-tap conv + per-image min/max. LDS-staged 64x64 tile (+15 halo),
// threads (16,16): each owns a 4-col x 4-row patch -> 34 ds_read_b128, 496 FMA.
__global__ __launch_bounds__(256) void vconv_k(const float* __restrict__ tmp,
                                               float* __restrict__ out,
                                               const float* __restrict__ wg,
                                               int* __restrict__ mm) {
    __shared__ float tile[94][64];               // 24.1 KB
    __shared__ float smin[4], smax[4];
    const int tx = threadIdx.x;                  // 0..15 col group
    const int ty = threadIdx.y;                  // 0..15 row group
    const int t  = ty * 16 + tx;
    const int img = blockIdx.z;
    const int x0 = blockIdx.x << 6;
    const int y0 = blockIdx.y << 6;
    const float* src = tmp + ((size_t)img << 18);
    // stage 94 rows x 16 float4 = 1504 float4s
#pragma unroll
    for (int it = 0; it < 6; ++it) {
        const int idx = t + it * 256;
        if (idx < 94 * 16) {
            const int rr = idx >> 4;
            const int c4 = idx & 15;
            const int y = y0 - RAD + rr;
            float4 v = make_float4(0.f, 0.f, 0.f, 0.f);
            if (y >= 0 && y < HWDIM)
                v = *(const float4*)(src + (size_t)y * HWDIM + x0 + (c4 << 2));
            *(float4*)&tile[rr][c4 << 2] = v;
        }
    }
    __syncthreads();
    float4 acc[4];
#pragma unroll
    for (int i = 0; i < 4; ++i) acc[i] = make_float4(0.f, 0.f, 0.f, 0.f);
#pragma unroll
    for (int k = 0; k < 34; ++k) {               // window rows
        const float4 v = *(const float4*)&tile[(ty << 2) + k][tx << 2];
#pragma unroll
        for (int i = 0; i < 4; ++i) {
            const int j = k - i;                 // weight index, compile-time
            if (j >= 0 && j < KLEN) {
                const float w = wg[j];
                acc[i].x += v.x * w;
                acc[i].y += v.y * w;
                acc[i].z += v.z * w;
                acc[i].w += v.w * w;
            }
        }
    }
    float* dst = out + ((size_t)img << 18);
    float lmin = INFINITY, lmax = -INFINITY;
#pragma unroll
    for (int i = 0; i < 4; ++i) {
        *(float4*)&dst[(size_t)(y0 + (ty << 2) + i) * HWDIM + x0 + (tx << 2)] = acc[i];
        lmin = fminf(lmin, fminf(fminf(acc[i].x, acc[i].y), fminf(acc[i].z, acc[i].w)));
        lmax = fmaxf(lmax, fmaxf(fmaxf(acc[i].x, acc[i].y), fmaxf(acc[i].z, acc[i].w)));
    }
    // wave butterfly -> block LDS reduce -> one atomic pair per block
#pragma unroll
    for (int off = 1; off < 64; off <<= 1) {
        lmin = fminf(lmin, __shfl_xor(lmin, off, 64));
        lmax = fmaxf(lmax, __shfl_xor(lmax, off, 64));
    }
    const int lane = t & 63, wid = t >> 6;
    if (lane == 0) { smin[wid] = lmin; smax[wid] = lmax; }
    __syncthreads();
    if (t == 0) {
        float bmin = fminf(fminf(smin[0], smin[1]), fminf(smin[2], smin[3]));
        float bmax = fmaxf(fmaxf(smax[0], smax[1]), fmaxf(smax[2], smax[3]));
        // all values >= 0 -> float ordering == int-bits ordering
        atomicMin(&mm[img * MM_STRIDE], __float_as_int(bmin));
        atomicMax(&mm[img * MM_STRIDE + 1], __float_as_int(bmax));
    }
}

// out = max((out - mn) / max(mx - mn, eps), clip(attn,0,1)), in place.
__global__ __launch_bounds__(256) void final_k(const float* __restrict__ attn,
                                               float* __restrict__ out,
                                               const int* __restrict__ mm) {
    const int img = blockIdx.x >> 6;             // 64 blocks of 4096 elems/image
    const float mn = __int_as_float(mm[img * MM_STRIDE]);
    const float mx = __int_as_float(mm[img * MM_STRIDE + 1]);
    const float inv = 1.0f / fmaxf(mx - mn, EPSV);
    const size_t base0 = ((size_t)blockIdx.x << 12) + ((size_t)threadIdx.x << 2);
#pragma unroll
    for (int h = 0; h < 4; ++h) {
        const size_t base = base0 + (size_t)h * 1024;
        float4 s = *(const float4*)(out + base);
        float4 a = *(const float4*)(attn + base);
        float4 o;
        o.x = fmaxf((s.x - mn) * inv, fminf(fmaxf(a.x, 0.f), 1.f));
        o.y = fmaxf((s.y - mn) * inv, fminf(fmaxf(a.y, 0.f), 1.f));
        o.z = fmaxf((s.z - mn) * inv, fminf(fmaxf(a.z, 0.f), 1.f));
        o.w = fmaxf((s.w - mn) * inv, fminf(fmaxf(a.w, 0.f), 1.f));
        *(float4*)(out + base) = o;
    }
}

extern "C" void kernel_launch(void* const* d_in, const int* in_sizes, int n_in,
                              void* d_out, int out_size, void* d_ws, size_t ws_size,
                              hipStream_t stream) {
    const float* attn = (const float*)d_in[0];
    const float* gk   = (const float*)d_in[1];
    float* out  = (float*)d_out;
    float* wsf  = (float*)d_ws;
    float* w1d  = wsf;
    int*   mm   = (int*)(wsf + 32);
    float* tmp  = wsf + 4096;          // 64 MB h-conv intermediate

    init_k<<<1, 128, 0, stream>>>(gk, w1d, mm);
    hconv_k<<<IMGS * HWDIM / 8, 256, 0, stream>>>(attn, tmp, w1d);   // 4096 blocks
    vconv_k<<<dim3(8, 8, IMGS), dim3(16, 16), 0, stream>>>(tmp, out, w1d, mm);
    final_k<<<IMGS * HWDIM * HWDIM / 4096, 256, 0, stream>>>(attn, out, mm);
}

// Round 7
// 110.065 us; speedup vs baseline: 3.8536x; 1.0092x over previous
//
#include <hip/hip_runtime.h>
#include <math.h>

#define IMGS 64
#define HWDIM 512
#define KLEN 31
#define RAD 15
#define EPSV 1e-3f
#define MM_STRIDE 32   // ints per image slot (one 128B cache line each)

// ws layout (floats):
//   [0..31)     : separable weights s[i]  (kernel[i][j] = s_i*s_j)
//   [32..2080)  : per-image min/max int bits, 32-int stride
// d_out carries the pre-norm conv result, normalized in place by final_k.
// No tmp buffer: h-conv intermediate lives only in LDS.

__global__ __launch_bounds__(128) void init_k(const float* __restrict__ gk,
                                              float* __restrict__ w,
                                              int* __restrict__ mm) {
    int t = threadIdx.x;
    if (t < KLEN) w[t] = sqrtf(gk[t * KLEN + t]);   // diag of s_i*s_j = s_i^2
    if (t < IMGS) { mm[t * MM_STRIDE] = 0x7F800000; mm[t * MM_STRIDE + 1] = 0; }
}

// Fused separable 31x31 conv per 64x64 output tile.
// Phase A: horizontal conv (clip fused) of 94 rows x 64 cols -> LDS.
// Phase B: vertical conv from LDS -> pre-norm out + per-image min/max atomics.
__global__ __launch_bounds__(256) void conv_k(const float* __restrict__ attn,
                                              float* __restrict__ out,
                                              const float* __restrict__ wg,
                                              int* __restrict__ mm) {
    __shared__ float inter[94 * 64];             // 23.5 KB
    __shared__ float smin[4], smax[4];
    const int t = threadIdx.x;
    const int img = blockIdx.z;
    const int x0 = blockIdx.x << 6;
    const int y0 = blockIdx.y << 6;
    const float* src = attn + ((size_t)img << 18);

    // ---- phase A: hconv rows [y0-15, y0+79) x cols [x0, x0+64) into LDS ----
#pragma unroll
    for (int it = 0; it < 6; ++it) {
        const int item = t + it * 256;           // 94 rows x 16 col-groups
        if (item < 94 * 16) {
            const int r  = item >> 4;
            const int cg = item & 15;
            const int y  = y0 - RAD + r;
            float4 o = make_float4(0.f, 0.f, 0.f, 0.f);
            if (y >= 0 && y < HWDIM) {
                const float4* row = (const float4*)(src + (size_t)y * HWDIM);
                const int gbase = (x0 >> 2) + cg - 4;
                float vv[36];
#pragma unroll
                for (int m = 0; m < 9; ++m) {
                    const int g = gbase + m;
                    float4 v = make_float4(0.f, 0.f, 0.f, 0.f);
                    if (g >= 0 && g < 128) v = row[g];
                    vv[4 * m + 0] = fminf(fmaxf(v.x, 0.f), 1.f);
                    vv[4 * m + 1] = fminf(fmaxf(v.y, 0.f), 1.f);
                    vv[4 * m + 2] = fminf(fmaxf(v.z, 0.f), 1.f);
                    vv[4 * m + 3] = fminf(fmaxf(v.w, 0.f), 1.f);
                }
                float* op = &o.x;
#pragma unroll
                for (int i = 0; i < 4; ++i) {
                    float a = 0.f;
#pragma unroll
                    for (int k = 0; k < KLEN; ++k) a += vv[1 + i + k] * wg[k];
                    op[i] = a;
                }
            }
            *(float4*)&inter[r * 64 + (cg << 2)] = o;   // zero for pad rows
        }
    }
    __syncthreads();

    // ---- phase B: vconv, each thread owns a 4-col x 4-row patch ----
    const int tx = t & 15;
    const int ty = t >> 4;
    float4 acc[4];
#pragma unroll
    for (int i = 0; i < 4; ++i) acc[i] = make_float4(0.f, 0.f, 0.f, 0.f);
#pragma unroll
    for (int k = 0; k < 34; ++k) {
        const float4 v = *(const float4*)&inter[((ty << 2) + k) * 64 + (tx << 2)];
#pragma unroll
        for (int i = 0; i < 4; ++i) {
            const int j = k - i;                 // weight index, compile-time
            if (j >= 0 && j < KLEN) {
                const float w = wg[j];
                acc[i].x += v.x * w;
                acc[i].y += v.y * w;
                acc[i].z += v.z * w;
                acc[i].w += v.w * w;
            }
        }
    }
    float* dst = out + ((size_t)img << 18);
    float lmin = INFINITY, lmax = -INFINITY;
#pragma unroll
    for (int i = 0; i < 4; ++i) {
        *(float4*)&dst[(size_t)(y0 + (ty << 2) + i) * HWDIM + x0 + (tx << 2)] = acc[i];
        lmin = fminf(lmin, fminf(fminf(acc[i].x, acc[i].y), fminf(acc[i].z, acc[i].w)));
        lmax = fmaxf(lmax, fmaxf(fmaxf(acc[i].x, acc[i].y), fmaxf(acc[i].z, acc[i].w)));
    }
    // wave butterfly -> block LDS reduce -> one atomic pair per block
#pragma unroll
    for (int off = 1; off < 64; off <<= 1) {
        lmin = fminf(lmin, __shfl_xor(lmin, off, 64));
        lmax = fmaxf(lmax, __shfl_xor(lmax, off, 64));
    }
    const int lane = t & 63, wid = t >> 6;
    if (lane == 0) { smin[wid] = lmin; smax[wid] = lmax; }
    __syncthreads();
    if (t == 0) {
        float bmin = fminf(fminf(smin[0], smin[1]), fminf(smin[2], smin[3]));
        float bmax = fmaxf(fmaxf(smax[0], smax[1]), fmaxf(smax[2], smax[3]));
        // all values >= 0 -> float ordering == int-bits ordering
        atomicMin(&mm[img * MM_STRIDE], __float_as_int(bmin));
        atomicMax(&mm[img * MM_STRIDE + 1], __float_as_int(bmax));
    }
}

// out = max((out - mn) / max(mx - mn, eps), clip(attn,0,1)), in place.
__global__ __launch_bounds__(256) void final_k(const float* __restrict__ attn,
                                               float* __restrict__ out,
                                               const int* __restrict__ mm) {
    const int img = blockIdx.x >> 6;             // 64 blocks of 4096 elems/image
    const float mn = __int_as_float(mm[img * MM_STRIDE]);
    const float mx = __int_as_float(mm[img * MM_STRIDE + 1]);
    const float inv = 1.0f / fmaxf(mx - mn, EPSV);
    const size_t base0 = ((size_t)blockIdx.x << 12) + ((size_t)threadIdx.x << 2);
#pragma unroll
    for (int h = 0; h < 4; ++h) {
        const size_t base = base0 + (size_t)h * 1024;
        float4 s = *(const float4*)(out + base);
        float4 a = *(const float4*)(attn + base);
        float4 o;
        o.x = fmaxf((s.x - mn) * inv, fminf(fmaxf(a.x, 0.f), 1.f));
        o.y = fmaxf((s.y - mn) * inv, fminf(fmaxf(a.y, 0.f), 1.f));
        o.z = fmaxf((s.z - mn) * inv, fminf(fmaxf(a.z, 0.f), 1.f));
        o.w = fmaxf((s.w - mn) * inv, fminf(fmaxf(a.w, 0.f), 1.f));
        *(float4*)(out + base) = o;
    }
}

extern "C" void kernel_launch(void* const* d_in, const int* in_sizes, int n_in,
                              void* d_out, int out_size, void* d_ws, size_t ws_size,
                              hipStream_t stream) {
    const float* attn = (const float*)d_in[0];
    const float* gk   = (const float*)d_in[1];
    float* out  = (float*)d_out;
    float* wsf  = (float*)d_ws;
    float* w1d  = wsf;
    int*   mm   = (int*)(wsf + 32);

    init_k<<<1, 128, 0, stream>>>(gk, w1d, mm);
    conv_k<<<dim3(8, 8, IMGS), dim3(256), 0, stream>>>(attn, out, w1d, mm);
    final_k<<<IMGS * HWDIM * HWDIM / 4096, 256, 0, stream>>>(attn, out, mm);
}